// Round 6
// baseline (319.729 us; speedup 1.0000x reference)
//
#include <hip/hip_runtime.h>
#include <hip/hip_bf16.h>
#include <stdint.h>

#define N_TOK 8192
#define DIN   1024
#define DOUT  1024
#define HID   1024
#define NE    8
#define CAP   0.8f   // 1 - EPS

typedef __attribute__((ext_vector_type(8))) short short8;
typedef __attribute__((ext_vector_type(4))) float floatx4;

__device__ __forceinline__ void async_load16(const void* g, void* l) {
  __builtin_amdgcn_global_load_lds(
      (const __attribute__((address_space(1))) void*)g,
      (__attribute__((address_space(3))) void*)l,
      16, 0, 0);
}

__device__ __forceinline__ unsigned short bf16_bits(float f) {
  return __builtin_bit_cast(unsigned short, __float2bfloat16(f));
}

// ---------------------------------------------------------------------------
// Selector, COALESCED-Wsel version (round-5, measured good: −19 us).
// 512 blocks x 256 thr; each wave owns 4 tokens; Wsel reads lane-contiguous,
// amortized over 4 tokens. Also zero-fills d_out and emits x_bf + sw.
// ---------------------------------------------------------------------------
__global__ __launch_bounds__(256) void selector_kernel(
    const float* __restrict__ x, const float* __restrict__ Wsel,
    const float* __restrict__ bsel,
    __hip_bfloat16* __restrict__ x_bf, float* __restrict__ sw,
    float4* __restrict__ out4)
{
  // fused out-zeroing: 512 blocks * 256 thr * 16 float4 = 8192*1024 floats
  {
    const int base = blockIdx.x * 4096 + threadIdx.x;
    const float4 z4 = {0.f, 0.f, 0.f, 0.f};
#pragma unroll
    for (int r = 0; r < 16; r++) out4[base + r * 256] = z4;
  }

  const int lane = threadIdx.x & 63;
  const int wave = threadIdx.x >> 6;
  const int tok0 = blockIdx.x * 16 + wave * 4;
  const float* xr = x + (size_t)tok0 * DIN;
  const float4* W4 = (const float4*)Wsel;

  float acc[4][8];
#pragma unroll
  for (int m = 0; m < 4; m++)
#pragma unroll
    for (int e = 0; e < 8; e++) acc[m][e] = 0.f;

#pragma unroll
  for (int i = 0; i < 16; i++) {
    const int d = lane + i * 64;
    const float4 wlo = W4[d * 2];      // lanes: 32-B stride -> coalesced
    const float4 whi = W4[d * 2 + 1];
#pragma unroll
    for (int m = 0; m < 4; m++) {
      const float xv = xr[m * DIN + d];  // lanes: 4-B stride -> coalesced
      acc[m][0] += xv * wlo.x; acc[m][1] += xv * wlo.y;
      acc[m][2] += xv * wlo.z; acc[m][3] += xv * wlo.w;
      acc[m][4] += xv * whi.x; acc[m][5] += xv * whi.y;
      acc[m][6] += xv * whi.z; acc[m][7] += xv * whi.w;
    }
  }
  // full-wave butterfly: afterwards every lane holds all 32 sums
#pragma unroll
  for (int off = 32; off >= 1; off >>= 1)
#pragma unroll
    for (int m = 0; m < 4; m++)
#pragma unroll
      for (int e = 0; e < 8; e++) acc[m][e] += __shfl_xor(acc[m][e], off);

  if (lane < 4) {
    const int n = tok0 + lane;
    float w[8];
    float mx = -1e30f;
#pragma unroll
    for (int e = 0; e < 8; e++) { w[e] = acc[lane][e] + bsel[e]; mx = fmaxf(mx, w[e]); }
    float s = 0.f;
#pragma unroll
    for (int e = 0; e < 8; e++) { w[e] = expf(w[e] - mx); s += w[e]; }
    const float inv = 1.f / s;
#pragma unroll
    for (int e = 0; e < 8; e++) w[e] *= inv;

    // stable descending argsort (insertion sort; strict < keeps ties stable)
    float wsrt[8]; int ord[8];
    for (int k = 0; k < 8; k++) {
      const float v = w[k];
      int j = k;
      while (j > 0 && wsrt[j - 1] < v) { wsrt[j] = wsrt[j - 1]; ord[j] = ord[j - 1]; j--; }
      wsrt[j] = v; ord[j] = k;
    }
    // capped cumulative sparse weights (sorted order)
    float cum = 0.f, sws[8];
    for (int k = 0; k < 8; k++) {
      cum += wsrt[k];
      const float capped = fminf(cum, CAP);
      sws[k] = fmaxf(capped - cum + wsrt[k], 0.f);
    }
    // faithful to torch.gather(sparse_weight, 1, index): sw[j] = sws[ord[j]]
    for (int j = 0; j < 8; j++) sw[(size_t)n * 8 + j] = sws[ord[j]];
  }

  // bf16 conversion of the wave's 4 rows (float4 loads are cache-warm)
  const float4* xr4 = (const float4*)xr;
  ushort4* xb4 = (ushort4*)(x_bf + (size_t)tok0 * DIN);
#pragma unroll
  for (int m = 0; m < 4; m++)
#pragma unroll
    for (int i = 0; i < 4; i++) {
      const int d4 = lane + i * 64;
      const float4 xv = xr4[m * 256 + d4];
      ushort4 p;
      p.x = bf16_bits(xv.x);
      p.y = bf16_bits(xv.y);
      p.z = bf16_bits(xv.z);
      p.w = bf16_bits(xv.w);
      xb4[m * 256 + d4] = p;
    }
}

// ---------------------------------------------------------------------------
// FUSED 1024-thread kernel: weight transpose/convert + per-expert compaction.
// grid (16,16,17) — unchanged from round 5.
// ---------------------------------------------------------------------------
__global__ __launch_bounds__(1024) void compact_convert_kernel(
    const float* __restrict__ sw, int* __restrict__ idx, int* __restrict__ cnt,
    const float* __restrict__ W1, const float* __restrict__ W2,
    __hip_bfloat16* __restrict__ W1t, __hip_bfloat16* __restrict__ W2t)
{
  const int z = blockIdx.z;
  const int t = threadIdx.x;

  if (z == 16) {
    const int bid = blockIdx.x + 16 * blockIdx.y;
    if (bid >= 8) return;
    const int e = bid;
    const int lane = t & 63;
    const int wv = t >> 6;
    __shared__ int wave_base[16];
    __shared__ int chunk_total;
    int base = 0;
#pragma unroll
    for (int c = 0; c < 8; c++) {
      const int tok = c * 1024 + t;
      const bool act = sw[(size_t)tok * 8 + e] > 0.f;
      const unsigned long long m = __ballot(act);
      const int before = __popcll(m & ((1ull << lane) - 1ull));
      if (lane == 0) wave_base[wv] = __popcll(m);
      __syncthreads();
      if (t == 0) {
        int s = 0;
        for (int w = 0; w < 16; w++) { const int v = wave_base[w]; wave_base[w] = s; s += v; }
        chunk_total = s;
      }
      __syncthreads();
      if (act) idx[e * N_TOK + base + wave_base[wv] + before] = tok;
      base += chunk_total;
      __syncthreads();   // protect wave_base/chunk_total before next chunk
    }
    if (t == 0) cnt[e] = base;
    return;
  }

  // ---- convert: W[e][r][c] fp32 -> Wt[e][c][r] bf16, 64x64 tile ----
  __shared__ unsigned short tile[64][65];
  const float* src = (z & 8) ? W2 : W1;
  __hip_bfloat16* dst = (z & 8) ? W2t : W1t;
  const int e = z & 7;
  src += (size_t)e * 1024 * 1024;
  unsigned short* dstu = (unsigned short*)dst + (size_t)e * 1024 * 1024;
  const int R = blockIdx.y * 64, C = blockIdx.x * 64;

  // load: thread (row = t>>4, col4 = t&15) reads float4 -> bf16 -> LDS
  {
    const int row = t >> 4;
    const int col4 = t & 15;
    const float4 v = *(const float4*)(src + (size_t)(R + row) * 1024 + C + col4 * 4);
    tile[row][col4 * 4 + 0] = bf16_bits(v.x);
    tile[row][col4 * 4 + 1] = bf16_bits(v.y);
    tile[row][col4 * 4 + 2] = bf16_bits(v.z);
    tile[row][col4 * 4 + 3] = bf16_bits(v.w);
  }
  __syncthreads();
  // store: thread (d = t>>4, j = t&15) writes dst[C+d][R + 4j .. 4j+3]
  {
    const int d = t >> 4;
    const int j = t & 15;
    ushort4 o;
    o.x = tile[j * 4 + 0][d];
    o.y = tile[j * 4 + 1][d];
    o.z = tile[j * 4 + 2][d];
    o.w = tile[j * 4 + 3][d];
    *(ushort4*)(dstu + (size_t)(C + d) * 1024 + R + j * 4) = o;
  }
}

// ---------------------------------------------------------------------------
// Compacted per-expert GEMM, 128x128 tile, BK=32, TRIPLE-buffered LDS with
// ONE raw barrier + ONE counted vmcnt per K-tile (no drains, no pins).
//
// Schedule per tile t: STAGE(t+2 -> buf[(t+2)%3]) ; s_waitcnt vmcnt(4)
// [certifies tile t+1: vmcnt retires in issue order, so <=4 outstanding
// means only t+2's 4 loads remain] ; ds_read+MFMA from buf[t%3] [tile t was
// certified by EVERY wave's vmcnt at iter t-1 + the end barrier] ; s_barrier
// [doubles as buffer-protect: all waves done reading buf[t%3] before anyone
// stages t+3 into it next iteration].
// Tile t's loads are in flight ~2 iterations (~1600 cy) — covers L3/HBM
// latency that r1's drain-at-barrier (~400 cy slack) could not.
// vs r2 (107 us): HALF the barriers, zero sched_barrier pins.
//
// MODE 0 (FC1): A = gather(x_bf, idx[e]);  hpool[e] = bf16(relu(A W1t^T + b1))
// MODE 1 (FC2): A = hpool[e];  out[idx[e][m]] += sw * (A W2t^T + b2)  (atomic)
// ---------------------------------------------------------------------------
#define BUFO (128 * 32)   // elements per LDS buffer (8 KB bf16)

template <int MODE>
__global__ __launch_bounds__(256, 2) void moe_gemm(
    const __hip_bfloat16* __restrict__ x_bf,
    __hip_bfloat16* __restrict__ hpool,
    const __hip_bfloat16* __restrict__ Wt,
    const float* __restrict__ biasAll,
    const float* __restrict__ sw,
    const int* __restrict__ idx, const int* __restrict__ cnt,
    float* __restrict__ out)
{
  const int e = blockIdx.z;
  const int count = cnt[e];
  const int m0 = blockIdx.y * 128;
  if (m0 >= count) return;
  const int n0 = blockIdx.x * 128;

  __shared__ __align__(16) __hip_bfloat16 sA[3 * BUFO];
  __shared__ __align__(16) __hip_bfloat16 sB[3 * BUFO];
  const int t = threadIdx.x;
  const int lane = t & 63;
  const int wave = t >> 6;
  const int wm = (wave & 1) * 64;
  const int wn = (wave >> 1) * 64;
  const int* idx_e = idx + e * N_TOK;
  const float* bias = biasAll + e * 1024;

  floatx4 acc[4][4];
#pragma unroll
  for (int i = 0; i < 4; i++)
#pragma unroll
    for (int j = 0; j < 4; j++) acc[i][j] = (floatx4){0.f, 0.f, 0.f, 0.f};

  // staging addresses: thread t loads 16B for rows sr and sr+64
  const int sr = t >> 2;
  const int sc = (t & 3) * 8;
  const __hip_bfloat16* Ag0;
  const __hip_bfloat16* Ag1;
  if (MODE == 0) {
    const int t0 = idx_e[min(m0 + sr, count - 1)];       // clamp tail (valid rows)
    const int t1 = idx_e[min(m0 + sr + 64, count - 1)];
    Ag0 = x_bf + (size_t)t0 * 1024 + sc;
    Ag1 = x_bf + (size_t)t1 * 1024 + sc;
  } else {
    const __hip_bfloat16* hp = hpool + (size_t)e * N_TOK * 1024;
    Ag0 = hp + (size_t)(m0 + sr) * 1024 + sc;            // tail reads scratch: finite
    Ag1 = hp + (size_t)(m0 + sr + 64) * 1024 + sc;
  }
  const __hip_bfloat16* Bg = Wt + (size_t)e * 1024 * 1024 + (size_t)(n0 + sr) * 1024 + sc;
  __hip_bfloat16* lA = &sA[sr * 32 + sc];
  __hip_bfloat16* lB = &sB[sr * 32 + sc];

  const int rf = lane & 15;
  const int k8 = (lane >> 4) * 8;
  const int roA = (wm + rf) * 32 + k8;
  const int roB = (wn + rf) * 32 + k8;

  // stage K-tile KT (col offset KT*32) into buffer WB
#define STAGE(KT, WB)                                                           \
  {                                                                             \
    const int kof = (KT) * 32;                                                  \
    async_load16(Ag0 + kof, lA + (WB) * BUFO);                                  \
    async_load16(Ag1 + kof, lA + (WB) * BUFO + 64 * 32);                        \
    async_load16(Bg + kof, lB + (WB) * BUFO);                                   \
    async_load16(Bg + (size_t)64 * 1024 + kof, lB + (WB) * BUFO + 64 * 32);     \
  }

  // one K-tile: optional stage of KT+2, counted wait, compute KT, barrier
#define P2ITER(KT, RB, WB, WAIT, DOSTAGE)                                       \
  {                                                                             \
    if (DOSTAGE) STAGE((KT) + 2, WB);                                           \
    asm volatile("s_waitcnt " WAIT ::: "memory");                               \
    const __hip_bfloat16* pA = &sA[(RB) * BUFO + roA];                          \
    const __hip_bfloat16* pB = &sB[(RB) * BUFO + roB];                          \
    short8 aF[4], bF[4];                                                        \
    _Pragma("unroll")                                                           \
    for (int i = 0; i < 4; i++) aF[i] = *(const short8*)(pA + i * 16 * 32);     \
    _Pragma("unroll")                                                           \
    for (int j = 0; j < 4; j++) bF[j] = *(const short8*)(pB + j * 16 * 32);     \
    __builtin_amdgcn_s_setprio(1);                                              \
    _Pragma("unroll")                                                           \
    for (int i = 0; i < 4; i++)                                                 \
      _Pragma("unroll")                                                         \
      for (int j = 0; j < 4; j++)                                               \
        acc[i][j] = __builtin_amdgcn_mfma_f32_16x16x32_bf16(aF[i], bF[j],       \
                                                            acc[i][j], 0, 0, 0);\
    __builtin_amdgcn_s_setprio(0);                                              \
    __builtin_amdgcn_s_barrier();                                               \
  }

  // prologue: tiles 0,1 staged; certify tile 0 for all waves
  STAGE(0, 0);
  STAGE(1, 1);
  asm volatile("s_waitcnt vmcnt(4)" ::: "memory");
  __builtin_amdgcn_s_barrier();

  // main loop: tiles 0..29, unrolled x3 for compile-time buffer indices
#pragma unroll 1
  for (int kt = 0; kt < 30; kt += 3) {
    P2ITER(kt,     0, 2, "vmcnt(4)", true);   // stage kt+2 -> buf2
    P2ITER(kt + 1, 1, 0, "vmcnt(4)", true);   // stage kt+3 -> buf0
    P2ITER(kt + 2, 2, 1, "vmcnt(4)", true);   // stage kt+4 -> buf1
  }
  // tails: tiles 30 (buf0) and 31 (buf1); certify 31 with a full drain once
  P2ITER(30, 0, 0, "vmcnt(0)", false);
  P2ITER(31, 1, 0, "vmcnt(0)", false);
#undef P2ITER
#undef STAGE

  // epilogue: C/D layout col = lane&15, row = (lane>>4)*4 + reg
  const int quad = lane >> 4;
  const int cn = lane & 15;
#pragma unroll
  for (int i = 0; i < 4; i++) {
#pragma unroll
    for (int r = 0; r < 4; r++) {
      const int gm = m0 + wm + i * 16 + quad * 4 + r;
      if (gm >= count) continue;
      int tok = 0; float swv = 0.f;
      if (MODE == 1) {
        tok = idx_e[gm];
        swv = sw[tok * 8 + e];
      }
#pragma unroll
      for (int j = 0; j < 4; j++) {
        const int gn = n0 + wn + j * 16 + cn;
        const float v = acc[i][j][r] + bias[gn];
        if (MODE == 0) {
          hpool[((size_t)e * N_TOK + gm) * 1024 + gn] = __float2bfloat16(fmaxf(v, 0.f));
        } else {
          unsafeAtomicAdd(&out[(size_t)tok * 1024 + gn], swv * v);
        }
      }
    }
  }
}

// ---------------------------------------------------------------------------
extern "C" void kernel_launch(void* const* d_in, const int* in_sizes, int n_in,
                              void* d_out, int out_size, void* d_ws, size_t ws_size,
                              hipStream_t stream) {
  const float* x    = (const float*)d_in[0];
  const float* Wsel = (const float*)d_in[1];
  const float* bsel = (const float*)d_in[2];
  const float* W1   = (const float*)d_in[3];
  const float* b1   = (const float*)d_in[4];
  const float* W2   = (const float*)d_in[5];
  const float* b2   = (const float*)d_in[6];
  float* out = (float*)d_out;

  char* ws = (char*)d_ws;
  __hip_bfloat16* x_bf = (__hip_bfloat16*)ws; ws += (size_t)N_TOK * DIN * 2;
  __hip_bfloat16* W1t  = (__hip_bfloat16*)ws; ws += (size_t)NE * DIN * HID * 2;
  __hip_bfloat16* W2t  = (__hip_bfloat16*)ws; ws += (size_t)NE * HID * DOUT * 2;
  float* sw            = (float*)ws;          ws += (size_t)N_TOK * NE * 4;
  int* idx             = (int*)ws;            ws += (size_t)NE * N_TOK * 4;
  int* cnt             = (int*)ws;            ws += 256;
  __hip_bfloat16* hpool = (__hip_bfloat16*)ws;  // NE*N_TOK*HID*2 = 134 MB

  selector_kernel<<<N_TOK / 16, 256, 0, stream>>>(x, Wsel, bsel, x_bf, sw,
                                                  (float4*)out);
  compact_convert_kernel<<<dim3(16, 16, 17), 1024, 0, stream>>>(
      sw, idx, cnt, W1, W2, W1t, W2t);

  moe_gemm<0><<<dim3(HID / 128, N_TOK / 128, NE), 256, 0, stream>>>(
      x_bf, hpool, W1t, b1, sw, idx, cnt, out);
  moe_gemm<1><<<dim3(DOUT / 128, N_TOK / 128, NE), 256, 0, stream>>>(
      x_bf, hpool, W2t, b2, sw, idx, cnt, out);
}

// Round 7
// 296.082 us; speedup vs baseline: 1.0799x; 1.0799x over previous
//
#include <hip/hip_runtime.h>
#include <hip/hip_bf16.h>
#include <stdint.h>

#define N_TOK 8192
#define DIN   1024
#define DOUT  1024
#define HID   1024
#define NE    8
#define CAP   0.8f   // 1 - EPS

typedef __attribute__((ext_vector_type(8))) short short8;
typedef __attribute__((ext_vector_type(4))) float floatx4;

__device__ __forceinline__ void async_load16(const void* g, void* l) {
  __builtin_amdgcn_global_load_lds(
      (const __attribute__((address_space(1))) void*)g,
      (__attribute__((address_space(3))) void*)l,
      16, 0, 0);
}

__device__ __forceinline__ unsigned short bf16_bits(float f) {
  return __builtin_bit_cast(unsigned short, __float2bfloat16(f));
}

// ---------------------------------------------------------------------------
// Selector, COALESCED-Wsel version (round-5, measured good: −19 us).
// 512 blocks x 256 thr; each wave owns 4 tokens; Wsel reads lane-contiguous,
// amortized over 4 tokens. Also zero-fills d_out and emits x_bf + sw.
// ---------------------------------------------------------------------------
__global__ __launch_bounds__(256) void selector_kernel(
    const float* __restrict__ x, const float* __restrict__ Wsel,
    const float* __restrict__ bsel,
    __hip_bfloat16* __restrict__ x_bf, float* __restrict__ sw,
    float4* __restrict__ out4)
{
  // fused out-zeroing: 512 blocks * 256 thr * 16 float4 = 8192*1024 floats
  {
    const int base = blockIdx.x * 4096 + threadIdx.x;
    const float4 z4 = {0.f, 0.f, 0.f, 0.f};
#pragma unroll
    for (int r = 0; r < 16; r++) out4[base + r * 256] = z4;
  }

  const int lane = threadIdx.x & 63;
  const int wave = threadIdx.x >> 6;
  const int tok0 = blockIdx.x * 16 + wave * 4;
  const float* xr = x + (size_t)tok0 * DIN;
  const float4* W4 = (const float4*)Wsel;

  float acc[4][8];
#pragma unroll
  for (int m = 0; m < 4; m++)
#pragma unroll
    for (int e = 0; e < 8; e++) acc[m][e] = 0.f;

#pragma unroll
  for (int i = 0; i < 16; i++) {
    const int d = lane + i * 64;
    const float4 wlo = W4[d * 2];      // lanes: 32-B stride -> coalesced
    const float4 whi = W4[d * 2 + 1];
#pragma unroll
    for (int m = 0; m < 4; m++) {
      const float xv = xr[m * DIN + d];  // lanes: 4-B stride -> coalesced
      acc[m][0] += xv * wlo.x; acc[m][1] += xv * wlo.y;
      acc[m][2] += xv * wlo.z; acc[m][3] += xv * wlo.w;
      acc[m][4] += xv * whi.x; acc[m][5] += xv * whi.y;
      acc[m][6] += xv * whi.z; acc[m][7] += xv * whi.w;
    }
  }
  // full-wave butterfly: afterwards every lane holds all 32 sums
#pragma unroll
  for (int off = 32; off >= 1; off >>= 1)
#pragma unroll
    for (int m = 0; m < 4; m++)
#pragma unroll
      for (int e = 0; e < 8; e++) acc[m][e] += __shfl_xor(acc[m][e], off);

  if (lane < 4) {
    const int n = tok0 + lane;
    float w[8];
    float mx = -1e30f;
#pragma unroll
    for (int e = 0; e < 8; e++) { w[e] = acc[lane][e] + bsel[e]; mx = fmaxf(mx, w[e]); }
    float s = 0.f;
#pragma unroll
    for (int e = 0; e < 8; e++) { w[e] = expf(w[e] - mx); s += w[e]; }
    const float inv = 1.f / s;
#pragma unroll
    for (int e = 0; e < 8; e++) w[e] *= inv;

    // stable descending argsort (insertion sort; strict < keeps ties stable)
    float wsrt[8]; int ord[8];
    for (int k = 0; k < 8; k++) {
      const float v = w[k];
      int j = k;
      while (j > 0 && wsrt[j - 1] < v) { wsrt[j] = wsrt[j - 1]; ord[j] = ord[j - 1]; j--; }
      wsrt[j] = v; ord[j] = k;
    }
    // capped cumulative sparse weights (sorted order)
    float cum = 0.f, sws[8];
    for (int k = 0; k < 8; k++) {
      cum += wsrt[k];
      const float capped = fminf(cum, CAP);
      sws[k] = fmaxf(capped - cum + wsrt[k], 0.f);
    }
    // faithful to torch.gather(sparse_weight, 1, index): sw[j] = sws[ord[j]]
    for (int j = 0; j < 8; j++) sw[(size_t)n * 8 + j] = sws[ord[j]];
  }

  // bf16 conversion of the wave's 4 rows (float4 loads are cache-warm)
  const float4* xr4 = (const float4*)xr;
  ushort4* xb4 = (ushort4*)(x_bf + (size_t)tok0 * DIN);
#pragma unroll
  for (int m = 0; m < 4; m++)
#pragma unroll
    for (int i = 0; i < 4; i++) {
      const int d4 = lane + i * 64;
      const float4 xv = xr4[m * 256 + d4];
      ushort4 p;
      p.x = bf16_bits(xv.x);
      p.y = bf16_bits(xv.y);
      p.z = bf16_bits(xv.z);
      p.w = bf16_bits(xv.w);
      xb4[m * 256 + d4] = p;
    }
}

// ---------------------------------------------------------------------------
// FUSED 1024-thread kernel: weight transpose/convert + per-expert compaction.
// grid (16,16,17) — unchanged from round 5.
// ---------------------------------------------------------------------------
__global__ __launch_bounds__(1024) void compact_convert_kernel(
    const float* __restrict__ sw, int* __restrict__ idx, int* __restrict__ cnt,
    const float* __restrict__ W1, const float* __restrict__ W2,
    __hip_bfloat16* __restrict__ W1t, __hip_bfloat16* __restrict__ W2t)
{
  const int z = blockIdx.z;
  const int t = threadIdx.x;

  if (z == 16) {
    const int bid = blockIdx.x + 16 * blockIdx.y;
    if (bid >= 8) return;
    const int e = bid;
    const int lane = t & 63;
    const int wv = t >> 6;
    __shared__ int wave_base[16];
    __shared__ int chunk_total;
    int base = 0;
#pragma unroll
    for (int c = 0; c < 8; c++) {
      const int tok = c * 1024 + t;
      const bool act = sw[(size_t)tok * 8 + e] > 0.f;
      const unsigned long long m = __ballot(act);
      const int before = __popcll(m & ((1ull << lane) - 1ull));
      if (lane == 0) wave_base[wv] = __popcll(m);
      __syncthreads();
      if (t == 0) {
        int s = 0;
        for (int w = 0; w < 16; w++) { const int v = wave_base[w]; wave_base[w] = s; s += v; }
        chunk_total = s;
      }
      __syncthreads();
      if (act) idx[e * N_TOK + base + wave_base[wv] + before] = tok;
      base += chunk_total;
      __syncthreads();   // protect wave_base/chunk_total before next chunk
    }
    if (t == 0) cnt[e] = base;
    return;
  }

  // ---- convert: W[e][r][c] fp32 -> Wt[e][c][r] bf16, 64x64 tile ----
  __shared__ unsigned short tile[64][65];
  const float* src = (z & 8) ? W2 : W1;
  __hip_bfloat16* dst = (z & 8) ? W2t : W1t;
  const int e = z & 7;
  src += (size_t)e * 1024 * 1024;
  unsigned short* dstu = (unsigned short*)dst + (size_t)e * 1024 * 1024;
  const int R = blockIdx.y * 64, C = blockIdx.x * 64;

  // load: thread (row = t>>4, col4 = t&15) reads float4 -> bf16 -> LDS
  {
    const int row = t >> 4;
    const int col4 = t & 15;
    const float4 v = *(const float4*)(src + (size_t)(R + row) * 1024 + C + col4 * 4);
    tile[row][col4 * 4 + 0] = bf16_bits(v.x);
    tile[row][col4 * 4 + 1] = bf16_bits(v.y);
    tile[row][col4 * 4 + 2] = bf16_bits(v.z);
    tile[row][col4 * 4 + 3] = bf16_bits(v.w);
  }
  __syncthreads();
  // store: thread (d = t>>4, j = t&15) writes dst[C+d][R + 4j .. 4j+3]
  {
    const int d = t >> 4;
    const int j = t & 15;
    ushort4 o;
    o.x = tile[j * 4 + 0][d];
    o.y = tile[j * 4 + 1][d];
    o.z = tile[j * 4 + 2][d];
    o.w = tile[j * 4 + 3][d];
    *(ushort4*)(dstu + (size_t)(C + d) * 1024 + R + j * 4) = o;
  }
}

// ---------------------------------------------------------------------------
// Compacted per-expert GEMM, 128x128 tile, BK=32, double-buffered LDS —
// round-5-exact structure (best measured: 83.6-84.4 us) with ONE change:
// __launch_bounds__(256, 4) instead of (256, 2).
//
// Rationale (r6 post-mortem): dur tracks ONLY occupancy across r0-r6
// (28% <-> 84 us, 22% <-> 105 us); latency hiding here is TLP (m114
// wave-level MFMA/stage co-scheduling), not ILP. VGPR=60 fits the 128-reg
// budget of 4 waves/SIMD; LDS 32 KB allows 5 blocks/CU. 4 blocks/CU doubles
// the waves available to hide the per-tile barrier drain.
//
// MODE 0 (FC1): A = gather(x_bf, idx[e]);  hpool[e] = bf16(relu(A W1t^T + b1))
// MODE 1 (FC2): A = hpool[e];  out[idx[e][m]] += sw * (A W2t^T + b2)  (atomic)
// ---------------------------------------------------------------------------
#define BUFO (128 * 32)   // elements per LDS buffer

template <int MODE>
__global__ __launch_bounds__(256, 4) void moe_gemm(
    const __hip_bfloat16* __restrict__ x_bf,
    __hip_bfloat16* __restrict__ hpool,
    const __hip_bfloat16* __restrict__ Wt,
    const float* __restrict__ biasAll,
    const float* __restrict__ sw,
    const int* __restrict__ idx, const int* __restrict__ cnt,
    float* __restrict__ out)
{
  const int e = blockIdx.z;
  const int count = cnt[e];
  const int m0 = blockIdx.y * 128;
  if (m0 >= count) return;
  const int n0 = blockIdx.x * 128;

  __shared__ __align__(16) __hip_bfloat16 sA[2 * BUFO];
  __shared__ __align__(16) __hip_bfloat16 sB[2 * BUFO];
  const int t = threadIdx.x;
  const int lane = t & 63;
  const int wave = t >> 6;
  const int wm = (wave & 1) * 64;
  const int wn = (wave >> 1) * 64;
  const int* idx_e = idx + e * N_TOK;
  const float* bias = biasAll + e * 1024;

  floatx4 acc[4][4];
#pragma unroll
  for (int i = 0; i < 4; i++)
#pragma unroll
    for (int j = 0; j < 4; j++) acc[i][j] = (floatx4){0.f, 0.f, 0.f, 0.f};

  // staging addresses: thread t loads 16B for rows sr and sr+64
  const int sr = t >> 2;
  const int sc = (t & 3) * 8;
  const __hip_bfloat16* Ag0;
  const __hip_bfloat16* Ag1;
  if (MODE == 0) {
    const int t0 = idx_e[min(m0 + sr, count - 1)];       // clamp tail (valid rows)
    const int t1 = idx_e[min(m0 + sr + 64, count - 1)];
    Ag0 = x_bf + (size_t)t0 * 1024 + sc;
    Ag1 = x_bf + (size_t)t1 * 1024 + sc;
  } else {
    const __hip_bfloat16* hp = hpool + (size_t)e * N_TOK * 1024;
    Ag0 = hp + (size_t)(m0 + sr) * 1024 + sc;            // tail reads scratch: finite
    Ag1 = hp + (size_t)(m0 + sr + 64) * 1024 + sc;
  }
  const __hip_bfloat16* Bg = Wt + (size_t)e * 1024 * 1024 + (size_t)(n0 + sr) * 1024 + sc;
  __hip_bfloat16* lA = &sA[sr * 32 + sc];
  __hip_bfloat16* lB = &sB[sr * 32 + sc];

  const int rf = lane & 15;
  const int k8 = (lane >> 4) * 8;
  const int roA = (wm + rf) * 32 + k8;
  const int roB = (wn + rf) * 32 + k8;

  // prologue: stage K-tile 0 into buffer 0
  async_load16(Ag0, lA);
  async_load16(Ag1, lA + 64 * 32);
  async_load16(Bg, lB);
  async_load16(Bg + (size_t)64 * 1024, lB + 64 * 32);
  __syncthreads();

  // STEP(kt, RB, WB): stage tile kt+1 into buffer WB, compute tile kt from RB.
#define STEP(KT, RB, WB)                                                        \
  {                                                                             \
    const int knext = ((KT) + 1) * 32;                                          \
    if (knext < 1024) {                                                         \
      async_load16(Ag0 + knext, lA + (WB) * BUFO);                              \
      async_load16(Ag1 + knext, lA + (WB) * BUFO + 64 * 32);                    \
      async_load16(Bg + knext, lB + (WB) * BUFO);                               \
      async_load16(Bg + (size_t)64 * 1024 + knext, lB + (WB) * BUFO + 64 * 32); \
    }                                                                           \
    const __hip_bfloat16* pA = &sA[(RB) * BUFO + roA];                          \
    const __hip_bfloat16* pB = &sB[(RB) * BUFO + roB];                          \
    short8 aF[4], bF[4];                                                        \
    _Pragma("unroll")                                                           \
    for (int i = 0; i < 4; i++) aF[i] = *(const short8*)(pA + i * 16 * 32);     \
    _Pragma("unroll")                                                           \
    for (int j = 0; j < 4; j++) bF[j] = *(const short8*)(pB + j * 16 * 32);     \
    _Pragma("unroll")                                                           \
    for (int i = 0; i < 4; i++)                                                 \
      _Pragma("unroll")                                                         \
      for (int j = 0; j < 4; j++)                                               \
        acc[i][j] = __builtin_amdgcn_mfma_f32_16x16x32_bf16(aF[i], bF[j],       \
                                                            acc[i][j], 0, 0, 0);\
    __syncthreads();                                                            \
  }

  for (int kt = 0; kt < 32; kt += 2) {
    STEP(kt, 0, 1);
    STEP(kt + 1, 1, 0);
  }
#undef STEP

  // epilogue: C/D layout col = lane&15, row = (lane>>4)*4 + reg
  const int quad = lane >> 4;
  const int cn = lane & 15;
#pragma unroll
  for (int i = 0; i < 4; i++) {
#pragma unroll
    for (int r = 0; r < 4; r++) {
      const int gm = m0 + wm + i * 16 + quad * 4 + r;
      if (gm >= count) continue;
      int tok = 0; float swv = 0.f;
      if (MODE == 1) {
        tok = idx_e[gm];
        swv = sw[tok * 8 + e];
      }
#pragma unroll
      for (int j = 0; j < 4; j++) {
        const int gn = n0 + wn + j * 16 + cn;
        const float v = acc[i][j][r] + bias[gn];
        if (MODE == 0) {
          hpool[((size_t)e * N_TOK + gm) * 1024 + gn] = __float2bfloat16(fmaxf(v, 0.f));
        } else {
          unsafeAtomicAdd(&out[(size_t)tok * 1024 + gn], swv * v);
        }
      }
    }
  }
}

// ---------------------------------------------------------------------------
extern "C" void kernel_launch(void* const* d_in, const int* in_sizes, int n_in,
                              void* d_out, int out_size, void* d_ws, size_t ws_size,
                              hipStream_t stream) {
  const float* x    = (const float*)d_in[0];
  const float* Wsel = (const float*)d_in[1];
  const float* bsel = (const float*)d_in[2];
  const float* W1   = (const float*)d_in[3];
  const float* b1   = (const float*)d_in[4];
  const float* W2   = (const float*)d_in[5];
  const float* b2   = (const float*)d_in[6];
  float* out = (float*)d_out;

  char* ws = (char*)d_ws;
  __hip_bfloat16* x_bf = (__hip_bfloat16*)ws; ws += (size_t)N_TOK * DIN * 2;
  __hip_bfloat16* W1t  = (__hip_bfloat16*)ws; ws += (size_t)NE * DIN * HID * 2;
  __hip_bfloat16* W2t  = (__hip_bfloat16*)ws; ws += (size_t)NE * HID * DOUT * 2;
  float* sw            = (float*)ws;          ws += (size_t)N_TOK * NE * 4;
  int* idx             = (int*)ws;            ws += (size_t)NE * N_TOK * 4;
  int* cnt             = (int*)ws;            ws += 256;
  __hip_bfloat16* hpool = (__hip_bfloat16*)ws;  // NE*N_TOK*HID*2 = 134 MB

  selector_kernel<<<N_TOK / 16, 256, 0, stream>>>(x, Wsel, bsel, x_bf, sw,
                                                  (float4*)out);
  compact_convert_kernel<<<dim3(16, 16, 17), 1024, 0, stream>>>(
      sw, idx, cnt, W1, W2, W1t, W2t);

  moe_gemm<0><<<dim3(HID / 128, N_TOK / 128, NE), 256, 0, stream>>>(
      x_bf, hpool, W1t, b1, sw, idx, cnt, out);
  moe_gemm<1><<<dim3(DOUT / 128, N_TOK / 128, NE), 256, 0, stream>>>(
      x_bf, hpool, W2t, b2, sw, idx, cnt, out);
}

// Round 8
// 295.740 us; speedup vs baseline: 1.0811x; 1.0012x over previous
//
#include <hip/hip_runtime.h>
#include <hip/hip_bf16.h>
#include <stdint.h>

#define N_TOK 8192
#define DIN   1024
#define DOUT  1024
#define HID   1024
#define NE    8
#define CAP   0.8f   // 1 - EPS

typedef __attribute__((ext_vector_type(8))) short short8;
typedef __attribute__((ext_vector_type(4))) float floatx4;

__device__ __forceinline__ void async_load16(const void* g, void* l) {
  __builtin_amdgcn_global_load_lds(
      (const __attribute__((address_space(1))) void*)g,
      (__attribute__((address_space(3))) void*)l,
      16, 0, 0);
}

__device__ __forceinline__ unsigned short bf16_bits(float f) {
  return __builtin_bit_cast(unsigned short, __float2bfloat16(f));
}

// ---------------------------------------------------------------------------
// Selector, COALESCED-Wsel version (round-5, measured good). Unchanged.
// ---------------------------------------------------------------------------
__global__ __launch_bounds__(256) void selector_kernel(
    const float* __restrict__ x, const float* __restrict__ Wsel,
    const float* __restrict__ bsel,
    __hip_bfloat16* __restrict__ x_bf, float* __restrict__ sw,
    float4* __restrict__ out4)
{
  {
    const int base = blockIdx.x * 4096 + threadIdx.x;
    const float4 z4 = {0.f, 0.f, 0.f, 0.f};
#pragma unroll
    for (int r = 0; r < 16; r++) out4[base + r * 256] = z4;
  }

  const int lane = threadIdx.x & 63;
  const int wave = threadIdx.x >> 6;
  const int tok0 = blockIdx.x * 16 + wave * 4;
  const float* xr = x + (size_t)tok0 * DIN;
  const float4* W4 = (const float4*)Wsel;

  float acc[4][8];
#pragma unroll
  for (int m = 0; m < 4; m++)
#pragma unroll
    for (int e = 0; e < 8; e++) acc[m][e] = 0.f;

#pragma unroll
  for (int i = 0; i < 16; i++) {
    const int d = lane + i * 64;
    const float4 wlo = W4[d * 2];
    const float4 whi = W4[d * 2 + 1];
#pragma unroll
    for (int m = 0; m < 4; m++) {
      const float xv = xr[m * DIN + d];
      acc[m][0] += xv * wlo.x; acc[m][1] += xv * wlo.y;
      acc[m][2] += xv * wlo.z; acc[m][3] += xv * wlo.w;
      acc[m][4] += xv * whi.x; acc[m][5] += xv * whi.y;
      acc[m][6] += xv * whi.z; acc[m][7] += xv * whi.w;
    }
  }
#pragma unroll
  for (int off = 32; off >= 1; off >>= 1)
#pragma unroll
    for (int m = 0; m < 4; m++)
#pragma unroll
      for (int e = 0; e < 8; e++) acc[m][e] += __shfl_xor(acc[m][e], off);

  if (lane < 4) {
    const int n = tok0 + lane;
    float w[8];
    float mx = -1e30f;
#pragma unroll
    for (int e = 0; e < 8; e++) { w[e] = acc[lane][e] + bsel[e]; mx = fmaxf(mx, w[e]); }
    float s = 0.f;
#pragma unroll
    for (int e = 0; e < 8; e++) { w[e] = expf(w[e] - mx); s += w[e]; }
    const float inv = 1.f / s;
#pragma unroll
    for (int e = 0; e < 8; e++) w[e] *= inv;

    float wsrt[8]; int ord[8];
    for (int k = 0; k < 8; k++) {
      const float v = w[k];
      int j = k;
      while (j > 0 && wsrt[j - 1] < v) { wsrt[j] = wsrt[j - 1]; ord[j] = ord[j - 1]; j--; }
      wsrt[j] = v; ord[j] = k;
    }
    float cum = 0.f, sws[8];
    for (int k = 0; k < 8; k++) {
      cum += wsrt[k];
      const float capped = fminf(cum, CAP);
      sws[k] = fmaxf(capped - cum + wsrt[k], 0.f);
    }
    for (int j = 0; j < 8; j++) sw[(size_t)n * 8 + j] = sws[ord[j]];
  }

  const float4* xr4 = (const float4*)xr;
  ushort4* xb4 = (ushort4*)(x_bf + (size_t)tok0 * DIN);
#pragma unroll
  for (int m = 0; m < 4; m++)
#pragma unroll
    for (int i = 0; i < 4; i++) {
      const int d4 = lane + i * 64;
      const float4 xv = xr4[m * 256 + d4];
      ushort4 p;
      p.x = bf16_bits(xv.x);
      p.y = bf16_bits(xv.y);
      p.z = bf16_bits(xv.z);
      p.w = bf16_bits(xv.w);
      xb4[m * 256 + d4] = p;
    }
}

// ---------------------------------------------------------------------------
// FUSED 1024-thread kernel: weight transpose/convert + compaction. Unchanged.
// ---------------------------------------------------------------------------
__global__ __launch_bounds__(1024) void compact_convert_kernel(
    const float* __restrict__ sw, int* __restrict__ idx, int* __restrict__ cnt,
    const float* __restrict__ W1, const float* __restrict__ W2,
    __hip_bfloat16* __restrict__ W1t, __hip_bfloat16* __restrict__ W2t)
{
  const int z = blockIdx.z;
  const int t = threadIdx.x;

  if (z == 16) {
    const int bid = blockIdx.x + 16 * blockIdx.y;
    if (bid >= 8) return;
    const int e = bid;
    const int lane = t & 63;
    const int wv = t >> 6;
    __shared__ int wave_base[16];
    __shared__ int chunk_total;
    int base = 0;
#pragma unroll
    for (int c = 0; c < 8; c++) {
      const int tok = c * 1024 + t;
      const bool act = sw[(size_t)tok * 8 + e] > 0.f;
      const unsigned long long m = __ballot(act);
      const int before = __popcll(m & ((1ull << lane) - 1ull));
      if (lane == 0) wave_base[wv] = __popcll(m);
      __syncthreads();
      if (t == 0) {
        int s = 0;
        for (int w = 0; w < 16; w++) { const int v = wave_base[w]; wave_base[w] = s; s += v; }
        chunk_total = s;
      }
      __syncthreads();
      if (act) idx[e * N_TOK + base + wave_base[wv] + before] = tok;
      base += chunk_total;
      __syncthreads();
    }
    if (t == 0) cnt[e] = base;
    return;
  }

  __shared__ unsigned short tile[64][65];
  const float* src = (z & 8) ? W2 : W1;
  __hip_bfloat16* dst = (z & 8) ? W2t : W1t;
  const int e = z & 7;
  src += (size_t)e * 1024 * 1024;
  unsigned short* dstu = (unsigned short*)dst + (size_t)e * 1024 * 1024;
  const int R = blockIdx.y * 64, C = blockIdx.x * 64;

  {
    const int row = t >> 4;
    const int col4 = t & 15;
    const float4 v = *(const float4*)(src + (size_t)(R + row) * 1024 + C + col4 * 4);
    tile[row][col4 * 4 + 0] = bf16_bits(v.x);
    tile[row][col4 * 4 + 1] = bf16_bits(v.y);
    tile[row][col4 * 4 + 2] = bf16_bits(v.z);
    tile[row][col4 * 4 + 3] = bf16_bits(v.w);
  }
  __syncthreads();
  {
    const int d = t >> 4;
    const int j = t & 15;
    ushort4 o;
    o.x = tile[j * 4 + 0][d];
    o.y = tile[j * 4 + 1][d];
    o.z = tile[j * 4 + 2][d];
    o.w = tile[j * 4 + 3][d];
    *(ushort4*)(dstu + (size_t)(C + d) * 1024 + R + j * 4) = o;
  }
}

// ---------------------------------------------------------------------------
// PHASE-INTERLEAVED grouped GEMM (T2+T3+T4+T5 port, round-8).
// 128x128 tile, BK=64, 4 waves, 64 KB LDS (2 blocks/CU), 16 K-tile quads.
//
// LDS layout (byte offsets into lds[]):
//   A[par][half] at (par*2+half)*8192   (half = 64 rows x 64 cols bf16, 8KB)
//   B[par][half] at 32768 + (par*2+half)*8192
// Swizzle (T2/rule 21): element (row, colByte) of a half lives at LDS byte
//   row*128 + (colByte ^ ((row&7)<<4)). global_load_lds writes linearly
//   (base + t*16), so the SOURCE address carries the inverse permutation
//   (same XOR, involution) and ds_reads apply the XOR. Bank math: 64 lanes
//   spread 2-per-16B-slot over all 32 banks (2-way = free) vs 8-way before.
// Schedule per K-tile quad kt (parity P=kt&1), 4 phases:
//   entry: s_waitcnt vmcnt(4)  [certifies A[kt] (staged last quad ph1-2) and
//          B[kt] (staged 2 quads ago); only B[kt+1]'s 4 loads may remain]
//          + s_barrier (all waves certified; also closes last quad's reads)
//   ph1: stage A[kt+1] half0 -> par PN ; read B[kt] frags to regs (8 ds_read)
//        + A m-frag0 ; setprio MFMA x8 ; barrier
//   ph2: stage A[kt+1] half1 ; m-frag1 ; barrier
//   ph3: stage B[kt+2] half0 -> par P [B[kt] reg-cached since ph1; 2 barriers
//        guarantee all waves done reading it] ; m-frag2 ; barrier
//   ph4: stage B[kt+2] half1 ; m-frag3   (quad-end barrier = next entry)
// vmcnt never 0 in the loop (T4); tails: quad14 stages only A[15], quad15
// stages nothing and enters on vmcnt(0).
// ---------------------------------------------------------------------------
template <int MODE>
__global__ __launch_bounds__(256, 2) void moe_gemm(
    const __hip_bfloat16* __restrict__ x_bf,
    __hip_bfloat16* __restrict__ hpool,
    const __hip_bfloat16* __restrict__ Wt,
    const float* __restrict__ biasAll,
    const float* __restrict__ sw,
    const int* __restrict__ idx, const int* __restrict__ cnt,
    float* __restrict__ out)
{
  const int e = blockIdx.z;
  const int count = cnt[e];
  const int m0 = blockIdx.y * 128;
  if (m0 >= count) return;
  const int n0 = blockIdx.x * 128;

  __shared__ __align__(16) char lds[65536];

  const int t = threadIdx.x;
  const int lane = t & 63;
  const int wave = t >> 6;
  const int wm = (wave & 1) * 64;
  const int wn = (wave >> 1) * 64;
  const int* idx_e = idx + e * N_TOK;
  const float* bias = biasAll + e * 1024;

  floatx4 acc[4][4];
#pragma unroll
  for (int i = 0; i < 4; i++)
#pragma unroll
    for (int j = 0; j < 4; j++) acc[i][j] = (floatx4){0.f, 0.f, 0.f, 0.f};

  // ---- staging source pointers (per-thread, pre-swizzled global col) ----
  const int srow = t >> 3;                        // local row / 32-row group
  const int scol = ((t & 7) * 16) ^ ((srow & 7) << 4);  // swizzled byte col
  const char* aSrc[2][2];
  const char* bSrc[2][2];
  const __hip_bfloat16* hp = hpool + (size_t)e * N_TOK * 1024;
#pragma unroll
  for (int h = 0; h < 2; h++)
#pragma unroll
    for (int j = 0; j < 2; j++) {
      const int rA = h * 64 + j * 32 + srow;      // 0..127 local row
      if (MODE == 0) {
        const int tok = idx_e[min(m0 + rA, count - 1)];
        aSrc[h][j] = (const char*)(x_bf + (size_t)tok * 1024) + scol;
      } else {
        aSrc[h][j] = (const char*)(hp + (size_t)(m0 + rA) * 1024) + scol;
      }
      bSrc[h][j] = (const char*)(Wt + (size_t)e * 1024 * 1024 +
                                 (size_t)(n0 + rA) * 1024) + scol;
    }

  // ---- ds_read address components ----
  const int fr = lane & 15;
  const int frx = (fr & 7) << 4;
  const int q16 = (lane >> 4) << 4;
  const int colk0 = (0 + q16) ^ frx;              // ks=0 byte col (swizzled)
  const int colk1 = (64 + q16) ^ frx;             // ks=1
  const int rowOff[4] = { (0 * 16 + fr) * 128, (1 * 16 + fr) * 128,
                          (2 * 16 + fr) * 128, (3 * 16 + fr) * 128 };
  const int aReg = (wave & 1) * 8192;             // A half = wave's m-half
  const int bReg = 32768 + (wave >> 1) * 8192;    // B half = wave's n-half

  short8 bF00, bF01, bF10, bF11, bF20, bF21, bF30, bF31;

#define STAGE_A(KT, PAR, H)                                                     \
  {                                                                             \
    async_load16(aSrc[H][0] + (KT) * 128, lds + ((PAR)*2 + (H)) * 8192 + t*16); \
    async_load16(aSrc[H][1] + (KT) * 128,                                       \
                 lds + ((PAR)*2 + (H)) * 8192 + 4096 + t*16);                   \
  }
#define STAGE_B(KT, PAR, H)                                                     \
  {                                                                             \
    async_load16(bSrc[H][0] + (KT) * 128,                                       \
                 lds + 32768 + ((PAR)*2 + (H)) * 8192 + t*16);                  \
    async_load16(bSrc[H][1] + (KT) * 128,                                       \
                 lds + 32768 + ((PAR)*2 + (H)) * 8192 + 4096 + t*16);           \
  }
#define RA(P, I, CK) (*(const short8*)(lds + (P)*16384 + aReg + rowOff[I] + (CK)))
#define RB(P, N, CK) (*(const short8*)(lds + (P)*16384 + bReg + rowOff[N] + (CK)))

#define PHASEM(P, I)                                                            \
  {                                                                             \
    const short8 a0 = RA(P, I, colk0);                                          \
    const short8 a1 = RA(P, I, colk1);                                          \
    __builtin_amdgcn_s_setprio(1);                                              \
    acc[I][0] = __builtin_amdgcn_mfma_f32_16x16x32_bf16(a0, bF00, acc[I][0], 0, 0, 0); \
    acc[I][0] = __builtin_amdgcn_mfma_f32_16x16x32_bf16(a1, bF01, acc[I][0], 0, 0, 0); \
    acc[I][1] = __builtin_amdgcn_mfma_f32_16x16x32_bf16(a0, bF10, acc[I][1], 0, 0, 0); \
    acc[I][1] = __builtin_amdgcn_mfma_f32_16x16x32_bf16(a1, bF11, acc[I][1], 0, 0, 0); \
    acc[I][2] = __builtin_amdgcn_mfma_f32_16x16x32_bf16(a0, bF20, acc[I][2], 0, 0, 0); \
    acc[I][2] = __builtin_amdgcn_mfma_f32_16x16x32_bf16(a1, bF21, acc[I][2], 0, 0, 0); \
    acc[I][3] = __builtin_amdgcn_mfma_f32_16x16x32_bf16(a0, bF30, acc[I][3], 0, 0, 0); \
    acc[I][3] = __builtin_amdgcn_mfma_f32_16x16x32_bf16(a1, bF31, acc[I][3], 0, 0, 0); \
    __builtin_amdgcn_s_setprio(0);                                              \
  }

#define QUAD(KT, P, PN, WAITS, DOA, DOB)                                        \
  {                                                                             \
    asm volatile("s_waitcnt " WAITS ::: "memory");                              \
    __builtin_amdgcn_s_barrier();                                               \
    if (DOA) STAGE_A((KT) + 1, PN, 0);                                          \
    bF00 = RB(P, 0, colk0); bF01 = RB(P, 0, colk1);                             \
    bF10 = RB(P, 1, colk0); bF11 = RB(P, 1, colk1);                             \
    bF20 = RB(P, 2, colk0); bF21 = RB(P, 2, colk1);                             \
    bF30 = RB(P, 3, colk0); bF31 = RB(P, 3, colk1);                             \
    PHASEM(P, 0);                                                               \
    __builtin_amdgcn_s_barrier();                                               \
    if (DOA) STAGE_A((KT) + 1, PN, 1);                                          \
    PHASEM(P, 1);                                                               \
    __builtin_amdgcn_s_barrier();                                               \
    if (DOB) STAGE_B((KT) + 2, P, 0);                                           \
    PHASEM(P, 2);                                                               \
    __builtin_amdgcn_s_barrier();                                               \
    if (DOB) STAGE_B((KT) + 2, P, 1);                                           \
    PHASEM(P, 3);                                                               \
  }

  // prologue: A[0] -> par0, B[0] -> par0, B[1] -> par1  (12 loads/thread)
  STAGE_A(0, 0, 0); STAGE_A(0, 0, 1);
  STAGE_B(0, 0, 0); STAGE_B(0, 0, 1);
  STAGE_B(1, 1, 0); STAGE_B(1, 1, 1);

  // quads 0..13: full steady state (stage A[kt+1], B[kt+2])
#pragma unroll 1
  for (int kt = 0; kt < 14; kt += 2) {
    QUAD(kt,     0, 1, "vmcnt(4)", 1, 1);
    QUAD(kt + 1, 1, 0, "vmcnt(4)", 1, 1);
  }
  // tails
  QUAD(14, 0, 1, "vmcnt(4)", 1, 0);   // stages A[15] only
  QUAD(15, 1, 0, "vmcnt(0)", 0, 0);   // nothing left to stage

#undef QUAD
#undef PHASEM
#undef RB
#undef RA
#undef STAGE_B
#undef STAGE_A

  // epilogue: C/D layout col = lane&15, row = (lane>>4)*4 + reg
  const int quad = lane >> 4;
  const int cn = lane & 15;
#pragma unroll
  for (int i = 0; i < 4; i++) {
#pragma unroll
    for (int r = 0; r < 4; r++) {
      const int gm = m0 + wm + i * 16 + quad * 4 + r;
      if (gm >= count) continue;
      int tok = 0; float swv = 0.f;
      if (MODE == 1) {
        tok = idx_e[gm];
        swv = sw[tok * 8 + e];
      }
#pragma unroll
      for (int j = 0; j < 4; j++) {
        const int gn = n0 + wn + j * 16 + cn;
        const float v = acc[i][j][r] + bias[gn];
        if (MODE == 0) {
          hpool[((size_t)e * N_TOK + gm) * 1024 + gn] = __float2bfloat16(fmaxf(v, 0.f));
        } else {
          unsafeAtomicAdd(&out[(size_t)tok * 1024 + gn], swv * v);
        }
      }
    }
  }
}

// ---------------------------------------------------------------------------
extern "C" void kernel_launch(void* const* d_in, const int* in_sizes, int n_in,
                              void* d_out, int out_size, void* d_ws, size_t ws_size,
                              hipStream_t stream) {
  const float* x    = (const float*)d_in[0];
  const float* Wsel = (const float*)d_in[1];
  const float* bsel = (const float*)d_in[2];
  const float* W1   = (const float*)d_in[3];
  const float* b1   = (const float*)d_in[4];
  const float* W2   = (const float*)d_in[5];
  const float* b2   = (const float*)d_in[6];
  float* out = (float*)d_out;

  char* ws = (char*)d_ws;
  __hip_bfloat16* x_bf = (__hip_bfloat16*)ws; ws += (size_t)N_TOK * DIN * 2;
  __hip_bfloat16* W1t  = (__hip_bfloat16*)ws; ws += (size_t)NE * DIN * HID * 2;
  __hip_bfloat16* W2t  = (__hip_bfloat16*)ws; ws += (size_t)NE * HID * DOUT * 2;
  float* sw            = (float*)ws;          ws += (size_t)N_TOK * NE * 4;
  int* idx             = (int*)ws;            ws += (size_t)NE * N_TOK * 4;
  int* cnt             = (int*)ws;            ws += 256;
  __hip_bfloat16* hpool = (__hip_bfloat16*)ws;  // NE*N_TOK*HID*2 = 134 MB

  selector_kernel<<<N_TOK / 16, 256, 0, stream>>>(x, Wsel, bsel, x_bf, sw,
                                                  (float4*)out);
  compact_convert_kernel<<<dim3(16, 16, 17), 1024, 0, stream>>>(
      sw, idx, cnt, W1, W2, W1t, W2t);

  moe_gemm<0><<<dim3(HID / 128, N_TOK / 128, NE), 256, 0, stream>>>(
      x_bf, hpool, W1t, b1, sw, idx, cnt, out);
  moe_gemm<1><<<dim3(DOUT / 128, N_TOK / 128, NE), 256, 0, stream>>>(
      x_bf, hpool, W2t, b2, sw, idx, cnt, out);
}